// Round 9
// baseline (367.611 us; speedup 1.0000x reference)
//
#include <hip/hip_runtime.h>
#include <hip/hip_bf16.h>
#include <stdint.h>

#define NN 50000
#define NE 800000
#define CC 96
#define NL 3
#define NMT 3125          // M-tiles (16 nodes each)
#define NUNITS 1563       // 2-mtile work units

// fp16 fragment-packed weights: per layer: 6 tcol x 6 sets (0-2 Wc gates, 3-5 Whh gates)
// x 3 ks x 64 lanes x 8 fp16 = 55296 elems = 108 KB
#define ELEMS_PER_LAYER 55296

typedef _Float16 f16x8 __attribute__((ext_vector_type(8)));
typedef float f32x4 __attribute__((ext_vector_type(4)));
typedef uint16_t u16x8 __attribute__((ext_vector_type(8)));

__device__ __forceinline__ uint16_t f2h(float f){
  _Float16 h = (_Float16)f;
  return __builtin_bit_cast(uint16_t, h);
}
__device__ __forceinline__ float h2f(uint16_t u){
  return (float)__builtin_bit_cast(_Float16, u);
}

__global__ void k_hist(const int* __restrict__ dstv, int* __restrict__ counts){
  int e = blockIdx.x*256 + threadIdx.x;
  if(e < NE) atomicAdd(&counts[dstv[e]], 1);
}

// Scan-free bucket assignment (CSR bucket order is arbitrary): wave-prefix-scan
// + one global-cursor atomic per wave.
__global__ void k_assign(const int* __restrict__ counts, int* __restrict__ offsets,
                         int* __restrict__ cursor, int* __restrict__ gcur){
  int i = blockIdx.x*256 + threadIdx.x;
  int lane = threadIdx.x & 63;
  int v = (i < NN) ? counts[i] : 0;
  int sum = v;
  #pragma unroll
  for(int d=1; d<64; d<<=1){
    int t = __shfl_up(sum, d, 64);
    if(lane >= d) sum += t;
  }
  int total = __shfl(sum, 63, 64);
  int base = 0;
  if(lane == 63) base = atomicAdd(gcur, total);
  base = __shfl(base, 63, 64);
  int off = base + sum - v;
  if(i < NN){ offsets[i] = off; cursor[i] = off; }
}

__global__ void k_fill(const int* __restrict__ srcv, const int* __restrict__ dstv,
                       int* __restrict__ cursor, int* __restrict__ ssrc){
  int e = blockIdx.x*256 + threadIdx.x;
  if(e < NE){
    int d = dstv[e];
    int pos = atomicAdd(&cursor[d], 1);
    ssrc[pos] = srcv[e];
  }
}

// Merged prep: f32->fp16 x table (idx < N8) + fragment-packed fp16 weights.
// fe(tcol,g2,ks,lane,j) = (((tcol*6+g2)*3+ks)*64+lane)*8+j; g2: 0-2 Wc r/z/n, 3-5 Whh r/z/n.
// B-frag (16x16x32): element (k = ks*32 + (lane>>4)*8 + j, n = lane&15).
__device__ __forceinline__ size_t frag_elem(int tcol, int g2, int ks, int lane, int j){
  return (((size_t)(tcol*6 + g2)*3 + ks)*64 + lane)*8 + j;
}
__global__ void k_prep(const float4* __restrict__ x, u16x8* __restrict__ xh,
                       const float* __restrict__ weight, const float* __restrict__ w_ih,
                       const float* __restrict__ w_hh, uint16_t* __restrict__ gw){
  int idx = blockIdx.x*256 + threadIdx.x;
  const int N8 = NN*CC/8;          // 600000
  if(idx < N8){
    float4 a = x[idx*2], b = x[idx*2+1];
    u16x8 o;
    o[0]=f2h(a.x); o[1]=f2h(a.y); o[2]=f2h(a.z); o[3]=f2h(a.w);
    o[4]=f2h(b.x); o[5]=f2h(b.y); o[6]=f2h(b.z); o[7]=f2h(b.w);
    xh[idx] = o;
    return;
  }
  int pidx = idx - N8;
  const int TOT1 = NL*288*CC;      // Wc: (l, col, k)
  const int TOT2 = 288*CC;         // Whh: (col, k), replicated to all layers
  if(pidx < TOT1){
    int k = pidx % CC;
    int col = (pidx / CC) % 288;
    int l = pidx / (CC*288);
    // Wc[k][col] = sum_k2 weight[l][k][k2] * w_ih[col][k2]
    const float4* wr = (const float4*)(weight + (size_t)(l*CC + k)*CC);
    const float4* ir = (const float4*)(w_ih + (size_t)col*CC);
    float acc = 0.f;
    #pragma unroll 4
    for(int k2=0;k2<CC/4;k2++){
      float4 a = wr[k2], b = ir[k2];
      acc += a.x*b.x + a.y*b.y + a.z*b.z + a.w*b.w;
    }
    int g = col / 96, cg = col % 96;
    int tcol = cg >> 4, n = cg & 15;
    int ks = k >> 5, r = (k & 31) >> 3, j = k & 7;
    int lane = r*16 + n;
    gw[(size_t)l*ELEMS_PER_LAYER + frag_elem(tcol, g, ks, lane, j)] = f2h(acc);
  } else {
    int idx2 = pidx - TOT1;
    if(idx2 < TOT2){
      int k = idx2 % CC;
      int col = idx2 / CC;
      uint16_t h = f2h(w_hh[(size_t)col*CC + k]);   // gh = x @ w_hh^T: B[k][col] = w_hh[col][k]
      int g = col / 96, cg = col % 96;
      int tcol = cg >> 4, n = cg & 15;
      int ks = k >> 5, r = (k & 31) >> 3, j = k & 7;
      int lane = r*16 + n;
      size_t fe = frag_elem(tcol, 3+g, ks, lane, j);
      #pragma unroll
      for(int l=0;l<NL;l++) gw[(size_t)l*ELEMS_PER_LAYER + fe] = h;
    }
  }
}

// CSR aggregation from fp16 table: thread = (node, c8), 16B gathers, 8-wide ssrc
// prefetch; f32 accumulate, fp16 s-table out.
__global__ void k_aggregate(const u16x8* __restrict__ xh, const int* __restrict__ offsets,
                            const int* __restrict__ counts, const int* __restrict__ ssrc,
                            u16x8* __restrict__ s16){
  int tid = blockIdx.x*256 + threadIdx.x;
  if(tid >= NN*12) return;
  int n = tid / 12;
  int c8 = tid - n*12;
  int o0 = offsets[n];
  int o1 = o0 + counts[n];
  float a[8];
  #pragma unroll
  for(int t=0;t<8;t++) a[t] = 0.f;
  int j = o0;
  for(; j+8 <= o1; j+=8){
    int s0 = ssrc[j],   s1 = ssrc[j+1], s2 = ssrc[j+2], s3 = ssrc[j+3];
    int s4 = ssrc[j+4], s5 = ssrc[j+5], s6 = ssrc[j+6], s7 = ssrc[j+7];
    u16x8 v0 = xh[(size_t)s0*12 + c8];
    u16x8 v1 = xh[(size_t)s1*12 + c8];
    u16x8 v2 = xh[(size_t)s2*12 + c8];
    u16x8 v3 = xh[(size_t)s3*12 + c8];
    u16x8 v4 = xh[(size_t)s4*12 + c8];
    u16x8 v5 = xh[(size_t)s5*12 + c8];
    u16x8 v6 = xh[(size_t)s6*12 + c8];
    u16x8 v7 = xh[(size_t)s7*12 + c8];
    #pragma unroll
    for(int t=0;t<8;t++)
      a[t] += ((h2f(v0[t])+h2f(v1[t]))+(h2f(v2[t])+h2f(v3[t])))
            + ((h2f(v4[t])+h2f(v5[t]))+(h2f(v6[t])+h2f(v7[t])));
  }
  for(; j < o1; j++){
    u16x8 v = xh[(size_t)ssrc[j]*12 + c8];
    #pragma unroll
    for(int t=0;t<8;t++) a[t] += h2f(v[t]);
  }
  u16x8 o;
  #pragma unroll
  for(int t=0;t<8;t++) o[t] = f2h(a[t]);
  s16[tid] = o;
}

#define MFMA16(A,B,C) __builtin_amdgcn_mfma_f32_16x16x32_f16(A,B,C,0,0,0)

__device__ __forceinline__ void gru_epilogue(
    int m, int tcol, int nidx, int quad,
    const f32x4& air, const f32x4& aiz, const f32x4& ain,
    const f32x4& ahr, const f32x4& ahz, const f32x4& ahn,
    const uint16_t* __restrict__ x16, const float* __restrict__ b_ih,
    const float* __restrict__ b_hh, float* __restrict__ out_f,
    uint16_t* __restrict__ out_h16)
{
  int c = tcol*16 + nidx;
  float bir_ = b_ih[c], biz_ = b_ih[CC+c], bin_ = b_ih[2*CC+c];
  float bhr_ = b_hh[c], bhz_ = b_hh[CC+c], bhn_ = b_hh[2*CC+c];
  #pragma unroll
  for(int r=0;r<4;r++){
    int node = m*16 + quad*4 + r;       // C/D: row = quad*4 + reg, col = lane&15
    float ir  = air[r] + bir_;
    float iz  = aiz[r] + biz_;
    float in_ = ain[r] + bin_;
    float hr  = ahr[r] + bhr_;
    float hz  = ahz[r] + bhz_;
    float hn  = ahn[r] + bhn_;
    float rg = 1.f/(1.f + __expf(-(ir+hr)));
    float zg = 1.f/(1.f + __expf(-(iz+hz)));
    float nv = in_ + rg*hn;
    float av = fminf(fabsf(nv), 15.f);
    float e2 = __expf(2.f*av);
    float tg = 1.f - 2.f/(e2 + 1.f);
    tg = (nv < 0.f)? -tg : tg;
    size_t oi = (size_t)node*CC + c;
    float hp = h2f(x16[oi]);            // h state lives in the fp16 table
    float h = (1.f - zg)*tg + zg*hp;
    if(out_f)   out_f[oi] = h;          // final layer only (d_out, f32)
    if(out_h16) out_h16[oi] = f2h(h);   // intermediate layers (fp16 ping-pong)
  }
}

// Fused dual-GEMM + GRU, single-barrier, 2 mtiles/wave: 108 KB fp16 layer
// weights staged to LDS once per block; each wave processes TWO 16-row mtiles,
// sharing every B-fragment read across both (halves total LDS read traffic vs
// 1 mtile/wave). 256 blocks x 384 threads = 1536 waves for 1563 units
// (grid-stride tail).
__global__ __launch_bounds__(384) void k_gru(
    const uint16_t* __restrict__ s16, const uint16_t* __restrict__ x16,
    const uint16_t* __restrict__ gw_l,
    const float* __restrict__ b_ih, const float* __restrict__ b_hh,
    float* __restrict__ out_f, uint16_t* __restrict__ out_h16)
{
  __shared__ __align__(16) uint16_t lw[ELEMS_PER_LAYER];   // 110592 B

  const int tid = threadIdx.x;
  // stage all 108 KB: 6912 uint4 chunks over 384 threads = 18 exact iterations
  {
    const uint4* src = (const uint4*)gw_l;
    uint4* dst = (uint4*)lw;
    #pragma unroll
    for(int i=0;i<18;i++){
      int chunk = i*384 + tid;
      dst[chunk] = src[chunk];
    }
  }
  __syncthreads();                      // the only barrier

  int wave = tid >> 6;
  int lane = tid & 63;
  int nidx = lane & 15;
  int quad = lane >> 4;

  for(int u = blockIdx.x + 256*wave; u < NUNITS; u += 1536){
    int m0 = 2*u;
    int m1 = 2*u + 1;
    bool v1 = (m1 < NMT);
    int m1c = v1 ? m1 : m0;

    // A fragments for both mtiles (A: m=lane&15, k=quad*8+j per ks)
    f16x8 as0[3], ax0[3], as1[3], ax1[3];
    {
      size_t r0 = (size_t)(m0*16 + nidx)*CC;
      size_t r1 = (size_t)(m1c*16 + nidx)*CC;
      #pragma unroll
      for(int ks=0; ks<3; ks++){
        int ko = ks*32 + quad*8;
        as0[ks] = *reinterpret_cast<const f16x8*>(s16 + r0 + ko);
        ax0[ks] = *reinterpret_cast<const f16x8*>(x16 + r0 + ko);
        as1[ks] = *reinterpret_cast<const f16x8*>(s16 + r1 + ko);
        ax1[ks] = *reinterpret_cast<const f16x8*>(x16 + r1 + ko);
      }
    }

    #pragma unroll 1
    for(int tcol=0; tcol<6; tcol++){
      f32x4 air0={0.f,0.f,0.f,0.f}, aiz0={0.f,0.f,0.f,0.f}, ain0={0.f,0.f,0.f,0.f};
      f32x4 ahr0={0.f,0.f,0.f,0.f}, ahz0={0.f,0.f,0.f,0.f}, ahn0={0.f,0.f,0.f,0.f};
      f32x4 air1={0.f,0.f,0.f,0.f}, aiz1={0.f,0.f,0.f,0.f}, ain1={0.f,0.f,0.f,0.f};
      f32x4 ahr1={0.f,0.f,0.f,0.f}, ahz1={0.f,0.f,0.f,0.f}, ahn1={0.f,0.f,0.f,0.f};

      #pragma unroll
      for(int ks=0; ks<3; ks++){
        const uint16_t* base = lw + ((size_t)tcol*18 + ks)*512 + lane*8;
        f16x8 b;
        b = *reinterpret_cast<const f16x8*>(base);
        air0 = MFMA16(as0[ks], b, air0);  air1 = MFMA16(as1[ks], b, air1);
        b = *reinterpret_cast<const f16x8*>(base + 1536);
        aiz0 = MFMA16(as0[ks], b, aiz0);  aiz1 = MFMA16(as1[ks], b, aiz1);
        b = *reinterpret_cast<const f16x8*>(base + 3072);
        ain0 = MFMA16(as0[ks], b, ain0);  ain1 = MFMA16(as1[ks], b, ain1);
        b = *reinterpret_cast<const f16x8*>(base + 4608);
        ahr0 = MFMA16(ax0[ks], b, ahr0);  ahr1 = MFMA16(ax1[ks], b, ahr1);
        b = *reinterpret_cast<const f16x8*>(base + 6144);
        ahz0 = MFMA16(ax0[ks], b, ahz0);  ahz1 = MFMA16(ax1[ks], b, ahz1);
        b = *reinterpret_cast<const f16x8*>(base + 7680);
        ahn0 = MFMA16(ax0[ks], b, ahn0);  ahn1 = MFMA16(ax1[ks], b, ahn1);
      }

      gru_epilogue(m0, tcol, nidx, quad, air0,aiz0,ain0,ahr0,ahz0,ahn0,
                   x16, b_ih, b_hh, out_f, out_h16);
      if(v1)
        gru_epilogue(m1, tcol, nidx, quad, air1,aiz1,ain1,ahr1,ahz1,ahn1,
                     x16, b_ih, b_hh, out_f, out_h16);
    }
  }
}

extern "C" void kernel_launch(void* const* d_in, const int* in_sizes, int n_in,
                              void* d_out, int out_size, void* d_ws, size_t ws_size,
                              hipStream_t stream){
  const float* x0     = (const float*)d_in[0];
  const int*   ei     = (const int*)d_in[1];
  const float* weight = (const float*)d_in[2];
  const float* w_ih   = (const float*)d_in[3];
  const float* w_hh   = (const float*)d_in[4];
  const float* b_ih   = (const float*)d_in[5];
  const float* b_hh   = (const float*)d_in[6];
  float* out = (float*)d_out;

  const int* srcv = ei;        // edge_index[0]
  const int* dstv = ei + NE;   // edge_index[1]

  char* ws = (char*)d_ws;
  size_t off = 0;
  auto carve = [&](size_t bytes)->char*{
    char* p = ws + off;
    off += (bytes + 255) & ~(size_t)255;
    return p;
  };
  int* counts   = (int*)carve((size_t)NN*4);
  int* offsets  = (int*)carve((size_t)NN*4);
  int* cursor   = (int*)carve((size_t)NN*4);
  int* gcur     = (int*)carve(4);
  int* ssrc     = (int*)carve((size_t)NE*4);
  uint16_t* s16 = (uint16_t*)carve((size_t)NN*CC*2);    // fp16 aggregate table
  uint16_t* xh16A = (uint16_t*)carve((size_t)NN*CC*2);  // fp16 h table ping
  uint16_t* xh16B = (uint16_t*)carve((size_t)NN*CC*2);  // fp16 h table pong
  uint16_t* gw  = (uint16_t*)carve((size_t)NL*ELEMS_PER_LAYER*2);

  // CSR build (once — edge structure shared by all 3 layers)
  hipMemsetAsync(counts, 0, (size_t)NN*4, stream);
  hipMemsetAsync(gcur, 0, 4, stream);
  k_hist<<<(NE+255)/256, 256, 0, stream>>>(dstv, counts);
  k_assign<<<(NN+255)/256, 256, 0, stream>>>(counts, offsets, cursor, gcur);
  k_fill<<<(NE+255)/256, 256, 0, stream>>>(srcv, dstv, cursor, ssrc);

  // fp16 x table + folded/fragment-packed weights, one dispatch
  k_prep<<<((NN*CC/8 + NL*288*CC + 288*CC)+255)/256, 256, 0, stream>>>(
      (const float4*)x0, (u16x8*)xh16A, weight, w_ih, w_hh, gw);

  uint16_t* xh_cur = xh16A;
  uint16_t* xh_nxt = xh16B;
  for(int l=0; l<NL; l++){
    k_aggregate<<<((NN*12)+255)/256, 256, 0, stream>>>((const u16x8*)xh_cur, offsets, counts, ssrc, (u16x8*)s16);
    float* out_f = (l==NL-1) ? out : nullptr;           // f32 only for final output
    uint16_t* oh = (l==NL-1) ? nullptr : xh_nxt;        // fp16 h for next layer
    k_gru<<<256, 384, 0, stream>>>(s16, xh_cur,
                                   gw + (size_t)l*ELEMS_PER_LAYER,
                                   b_ih, b_hh, out_f, oh);
    xh_cur = xh_nxt; xh_nxt = (xh_cur == xh16A) ? xh16B : xh16A;
  }
}